// Round 9
// baseline (1927.647 us; speedup 1.0000x reference)
//
#include <hip/hip_runtime.h>

#define RES 1024
#define SEQ 512

typedef _Float16 f16;
typedef _Float16 half8 __attribute__((ext_vector_type(8)));
typedef float f32x4 __attribute__((ext_vector_type(4)));
typedef float f32x2 __attribute__((ext_vector_type(2), aligned(4)));
typedef unsigned int uint4v __attribute__((ext_vector_type(4)));

// LDS partial-sum planes [w8][n][r][c], odd row-stride 19 (champion layout).
// Plane 0 = chain A, plane 1 = chain B (fixed mapping).
#define PST 19
#define PPL 10240   // plane stride in floats (content 9728)
#define PIDX(w8, n, rr, cc) ((((w8) * 4 + (n)) * 16 + (rr)) * PST + (cc))

// Workspace (memset 0 each launch):
//   [0,512K) hp0 | [512K,1M) hp1 | [1M,1.5M) hm0 | [1.5M,2M) hm1 | [2M,+1K) xcdmap
//
// Grid: 256 wgs x 512 threads. wg -> (pair p, slice w):
//   p = (bx&7)*2 + ((bx>>3)&1), w = bx>>4.
// Pair p owns rows [p*16,p*16+16): chain A = rows 0-7, chain B = rows 8-15
// (independent recurrences). wg w owns cols [w*64,w*64+64); wave k polls
// K-range [k*128,(k+1)*128) of the needed 8 rows (duplicated to 16 MFMA rows
// via col&7 — r19-proven).
//
// Round-23 — TWO-CHAIN LATENCY HIDING. The exchange RTT (~2300cy, r19-
// calibrated) is serialized once per step in the champion. Chains A and B are
// independent: each phase issues the OPPOSITE chain's poll at its top and
// waits with a counted `s_waitcnt vmcnt(4)` (4 newest = just-issued loads;
// vmcnt retires in order, so <=4 outstanding proves the current chain's loads
// and all stores retired — exact for all waves). The RTT rides under the
// opposite phase's compute. Phase barrier = lgkmcnt(0) + raw s_barrier (LDS
// visibility without draining the in-flight global loads). Two barriers per
// superstep = champion's count -> phase-locking preserved (r22 lesson).
// x is LDS-staged so no compiler-inserted vmcnt touches the pipeline.
// Tags/buffers/mirror fallback byte-identical to the champion protocol.

__device__ __forceinline__ float fast_tanh(float v) {
  float vc = fminf(15.0f, fmaxf(-15.0f, v));
  float e = __expf(2.0f * vc);
  return (e - 1.0f) * __builtin_amdgcn_rcpf(e + 1.0f);
}

// issue 4 loads, NO wait (pipeline fill)
#define ISSUE4(R0, R1, R2, R3, ptr)                                     \
  asm volatile(                                                         \
      "global_load_dwordx4 %0, %4, off sc0 sc1\n\t"                     \
      "global_load_dwordx4 %1, %4, off offset:64 sc0 sc1\n\t"           \
      "global_load_dwordx4 %2, %4, off offset:128 sc0 sc1\n\t"          \
      "global_load_dwordx4 %3, %4, off offset:192 sc0 sc1"              \
      : "=&v"(R0), "=&v"(R1), "=&v"(R2), "=&v"(R3) : "v"(ptr) : "memory")

// counted wait: 4 newest ops (the just-issued opposite-chain loads) may remain
#define WAIT_VM4(R0, R1, R2, R3)                                        \
  do {                                                                  \
    asm volatile("s_waitcnt vmcnt(4)"                                   \
                 : "+v"(R0), "+v"(R1), "+v"(R2), "+v"(R3)::"memory");   \
    __builtin_amdgcn_sched_barrier(0);                                  \
  } while (0)

#define WAIT_VM0(R0, R1, R2, R3)                                        \
  do {                                                                  \
    asm volatile("s_waitcnt vmcnt(0)"                                   \
                 : "+v"(R0), "+v"(R1), "+v"(R2), "+v"(R3)::"memory");   \
    __builtin_amdgcn_sched_barrier(0);                                  \
  } while (0)

// blocking reload (retry path) — champion semantics
#define FULL_LOAD4(R0, R1, R2, R3, ptr)                                 \
  do {                                                                  \
    asm volatile(                                                       \
        "global_load_dwordx4 %0, %4, off sc0 sc1\n\t"                   \
        "global_load_dwordx4 %1, %4, off offset:64 sc0 sc1\n\t"         \
        "global_load_dwordx4 %2, %4, off offset:128 sc0 sc1\n\t"        \
        "global_load_dwordx4 %3, %4, off offset:192 sc0 sc1\n\t"        \
        "s_waitcnt vmcnt(0)"                                            \
        : "=&v"(R0), "=&v"(R1), "=&v"(R2), "=&v"(R3) : "v"(ptr)         \
        : "memory");                                                    \
    __builtin_amdgcn_sched_barrier(0);                                  \
  } while (0)

// LDS-visibility barrier that does NOT drain vmcnt (keeps loads in flight)
#define PHASE_BARRIER()                                                 \
  do {                                                                  \
    asm volatile("s_waitcnt lgkmcnt(0)" ::: "memory");                  \
    __builtin_amdgcn_sched_barrier(0);                                  \
    __builtin_amdgcn_s_barrier();                                       \
    __builtin_amdgcn_sched_barrier(0);                                  \
  } while (0)

__device__ __forceinline__ bool tags_ok(half8 A0, half8 A1, half8 A2, half8 A3,
                                        unsigned int tagr) {
  const uint4v b0 = __builtin_bit_cast(uint4v, A0);
  const uint4v b1 = __builtin_bit_cast(uint4v, A1);
  const uint4v b2 = __builtin_bit_cast(uint4v, A2);
  const uint4v b3 = __builtin_bit_cast(uint4v, A3);
  unsigned int d =
      (b0.x ^ tagr) | (b0.y ^ tagr) | (b0.z ^ tagr) | (b0.w ^ tagr) |
      (b1.x ^ tagr) | (b1.y ^ tagr) | (b1.z ^ tagr) | (b1.w ^ tagr) |
      (b2.x ^ tagr) | (b2.y ^ tagr) | (b2.z ^ tagr) | (b2.w ^ tagr) |
      (b3.x ^ tagr) | (b3.y ^ tagr) | (b3.z ^ tagr) | (b3.w ^ tagr);
  return ((d & 1u) == 0u);
}

__global__ __launch_bounds__(512, 2) void res_recur_kernel(
    const float* __restrict__ x,      // [256][512]
    const float* __restrict__ W_in,   // [1024]
    const float* __restrict__ W_res,  // [1024][1024]
    f16* __restrict__ hp0,            // primary buffers
    f16* __restrict__ hp1,
    f16* __restrict__ hm0,            // mirror buffers (fallback groups only)
    f16* __restrict__ hm1,
    unsigned int* __restrict__ xcdmap)
{
  // P planes 81,920B + x 32,768B ≈ 115KB -> 1 wg/CU (round-14 lever preserved)
  __shared__ float P[2][PPL];
  __shared__ float x_s[16][SEQ];
  __shared__ unsigned char xmap_s[256];
  __shared__ int l2mode_s;

  const int tid  = threadIdx.x;
  const int wave = tid >> 6;
  const int lane = tid & 63;
  const int col  = lane & 15;
  const int kq   = (lane >> 4) & 3;

  const int bx = blockIdx.x;
  const int p  = (bx & 7) * 2 + ((bx >> 3) & 1);
  const int w  = bx >> 4;

  // ---- publish my XCC id (write-through agent store -> globally visible)
  unsigned int myxcc;
  asm volatile("s_getreg_b32 %0, hwreg(HW_REG_XCC_ID, 0, 8)" : "=s"(myxcc));
  if (tid == 0)
    __hip_atomic_store(&xcdmap[bx], (myxcc & 0xffu) + 1u, __ATOMIC_RELAXED,
                       __HIP_MEMORY_SCOPE_AGENT);

  // ---- W_res fragments (register-resident; shared by BOTH chains).
  half8 Wf[4][4];
#pragma unroll
  for (int n = 0; n < 4; ++n) {
    const float* Wr = W_res + (size_t)(w * 64 + n * 16 + col) * RES + wave * 128 + kq * 8;
#pragma unroll
    for (int ks = 0; ks < 4; ++ks) {
      f32x4 lo = *(const f32x4*)(Wr + ks * 32);
      f32x4 hi = *(const f32x4*)(Wr + ks * 32 + 4);
      half8 f;
#pragma unroll
      for (int j = 0; j < 4; ++j) { f[j] = (f16)lo[j]; f[j + 4] = (f16)hi[j]; }
      Wf[n][ks] = f;
    }
  }

  // ---- stage this pair's 16 x-rows into LDS (keeps the loop free of
  // compiler-managed global loads that would entangle vmcnt)
  for (int idx = tid; idx < 2048; idx += 512) {
    int row = idx >> 7, c4 = (idx & 127) * 4;
    *(f32x4*)&x_s[row][c4] = *(const f32x4*)(x + (size_t)(p * 16 + row) * SEQ + c4);
  }

  // ---- gather all 256 XCC ids
  if (tid < 256) {
    const unsigned int* ap = xcdmap + tid;
    unsigned int v;
    do {
      asm volatile("global_load_dword %0, %1, off sc0 sc1\n\t"
                   "s_waitcnt vmcnt(0)"
                   : "=&v"(v) : "v"(ap) : "memory");
    } while (v == 0u);
    xmap_s[tid] = (unsigned char)v;
  }
  __syncthreads();
  if (tid == 0) {
    const int base = (p >> 1) + 8 * (p & 1);   // bx of this pair's w=0 member
    const unsigned char ref = xmap_s[base];
    int ok = 1, cnt = 0;
    for (int i = 0; i < 256; ++i) cnt += (xmap_s[i] == ref) ? 1 : 0;
    for (int k = 0; k < 16; ++k) ok &= (xmap_s[base + 16 * k] == ref) ? 1 : 0;
    l2mode_s = (ok && cnt <= 64) ? 1 : 0;
  }
  __syncthreads();
  const bool l2mode = (l2mode_s != 0);

  // ---- epilogue mapping (tid<256): 8 rows x 32 col-pairs per phase
  const bool epi = (tid < 256);        // wave-uniform (waves 0-3)
  const int r8  = (tid >> 5) & 7;      // row within 8-row chain
  const int cp  = tid & 31;
  const int n_e = cp >> 3;
  const int c0  = (cp & 7) * 2;
  const float win_lo = W_in[w * 64 + n_e * 16 + c0];
  const float win_hi = W_in[w * 64 + n_e * 16 + c0 + 1];
  const unsigned int houtA =
      ((unsigned)(p * 16 + r8) * RES + w * 64 + n_e * 16 + c0) >> 1;
  const unsigned int houtB = houtA + (8u * RES >> 1);

  // A-operand bases: 8 rows duplicated to 16 MFMA rows via col&7
  const size_t aoffA = (size_t)(p * 16 + (col & 7)) * RES + wave * 128 + kq * 8;
  const size_t aoffB = aoffA + (size_t)8 * RES;

  half8 AR0, AR1, AR2, AR3;   // chain-A operand pipeline regs
  half8 BR0, BR1, BR2, BR3;   // chain-B operand pipeline regs

  for (int s = 0; s < SEQ; ++s) {
    const unsigned int tagr = (unsigned)(((s >> 1) + (s & 1)) & 1);
    const unsigned int tagw = (unsigned)((((s + 1) >> 1) + ((s + 1) & 1)) & 1);
    f16* hrd = (s & 1) ? hp1 : hp0;   // holds h(s)
    f16* hwr = (s & 1) ? hp0 : hp1;   // receives h(s+1)
    f16* mrd = (s & 1) ? hm1 : hm0;
    f16* mwr = (s & 1) ? hm0 : hm1;

    // ================= PHASE A (rows 0-7) =================
    f32x4 acc[4];
#pragma unroll
    for (int n = 0; n < 4; ++n) acc[n] = (f32x4){0.f, 0.f, 0.f, 0.f};

    if (s > 0) {
      // top-of-phase: launch chain-B's poll for THIS step (hB(s) stored a
      // full phase ago -> committed), then wait for chain-A's pipeline regs.
      ISSUE4(BR0, BR1, BR2, BR3, hrd + aoffB);
      WAIT_VM4(AR0, AR1, AR2, AR3);
      if (!tags_ok(AR0, AR1, AR2, AR3, tagr)) {
        unsigned int it = 0;
        do {
          ++it;
          const f16* Pp = (!l2mode && ((it & 7u) == 0u)) ? (mrd + aoffA)
                                                         : (hrd + aoffA);
          FULL_LOAD4(AR0, AR1, AR2, AR3, Pp);
        } while (!tags_ok(AR0, AR1, AR2, AR3, tagr));
      }
#pragma unroll
      for (int n = 0; n < 4; ++n) acc[n] = __builtin_amdgcn_mfma_f32_16x16x32_f16(AR0, Wf[n][0], acc[n], 0, 0, 0);
#pragma unroll
      for (int n = 0; n < 4; ++n) acc[n] = __builtin_amdgcn_mfma_f32_16x16x32_f16(AR1, Wf[n][1], acc[n], 0, 0, 0);
#pragma unroll
      for (int n = 0; n < 4; ++n) acc[n] = __builtin_amdgcn_mfma_f32_16x16x32_f16(AR2, Wf[n][2], acc[n], 0, 0, 0);
#pragma unroll
      for (int n = 0; n < 4; ++n) acc[n] = __builtin_amdgcn_mfma_f32_16x16x32_f16(AR3, Wf[n][3], acc[n], 0, 0, 0);
    }

#pragma unroll
    for (int n = 0; n < 4; ++n)
#pragma unroll
      for (int j = 0; j < 4; ++j)
        P[0][PIDX(wave, n, kq * 4 + j, col)] = acc[n][j];

    PHASE_BARRIER();   // LDS visible; global loads stay in flight

    if (epi) {
      float s_lo = 0.f, s_hi = 0.f;
#pragma unroll
      for (int w8 = 0; w8 < 8; ++w8) {
        f32x2 t = *(const f32x2*)&P[0][PIDX(w8, n_e, r8, c0)];
        s_lo += t.x;
        s_hi += t.y;
      }
      float u = x_s[r8][s];
      float v_lo = fast_tanh(s_lo + u * win_lo);
      float v_hi = fast_tanh(s_hi + u * win_hi);
      union { f16 h[2]; unsigned int u32; } pk;
      pk.h[0] = (f16)v_lo; pk.h[1] = (f16)v_hi;
      pk.u32  = (pk.u32 & ~1u) | tagw;
      ((unsigned int*)hwr)[houtA] = pk.u32;          // plain WB store
      if (!l2mode)
        __hip_atomic_store(&((unsigned int*)mwr)[houtA], pk.u32,
                           __ATOMIC_RELAXED, __HIP_MEMORY_SCOPE_AGENT);
    }

    // ================= PHASE B (rows 8-15) =================
    f32x4 accB[4];
#pragma unroll
    for (int n = 0; n < 4; ++n) accB[n] = (f32x4){0.f, 0.f, 0.f, 0.f};

    if (s < SEQ - 1) {
      // launch chain-A's poll for step s+1 (hA(s+1) stored just above by the
      // pair's 16 wgs; commit races are caught by tags at the next wait)
      ISSUE4(AR0, AR1, AR2, AR3, hwr + aoffA);
    }
    if (s > 0) {
      if (s < SEQ - 1) { WAIT_VM4(BR0, BR1, BR2, BR3); }
      else             { WAIT_VM0(BR0, BR1, BR2, BR3); }
      if (!tags_ok(BR0, BR1, BR2, BR3, tagr)) {
        unsigned int it = 0;
        do {
          ++it;
          const f16* Pp = (!l2mode && ((it & 7u) == 0u)) ? (mrd + aoffB)
                                                         : (hrd + aoffB);
          FULL_LOAD4(BR0, BR1, BR2, BR3, Pp);
        } while (!tags_ok(BR0, BR1, BR2, BR3, tagr));
      }
#pragma unroll
      for (int n = 0; n < 4; ++n) accB[n] = __builtin_amdgcn_mfma_f32_16x16x32_f16(BR0, Wf[n][0], accB[n], 0, 0, 0);
#pragma unroll
      for (int n = 0; n < 4; ++n) accB[n] = __builtin_amdgcn_mfma_f32_16x16x32_f16(BR1, Wf[n][1], accB[n], 0, 0, 0);
#pragma unroll
      for (int n = 0; n < 4; ++n) accB[n] = __builtin_amdgcn_mfma_f32_16x16x32_f16(BR2, Wf[n][2], accB[n], 0, 0, 0);
#pragma unroll
      for (int n = 0; n < 4; ++n) accB[n] = __builtin_amdgcn_mfma_f32_16x16x32_f16(BR3, Wf[n][3], accB[n], 0, 0, 0);
    }

#pragma unroll
    for (int n = 0; n < 4; ++n)
#pragma unroll
      for (int j = 0; j < 4; ++j)
        P[1][PIDX(wave, n, kq * 4 + j, col)] = accB[n][j];

    PHASE_BARRIER();

    if (epi) {
      float s_lo = 0.f, s_hi = 0.f;
#pragma unroll
      for (int w8 = 0; w8 < 8; ++w8) {
        f32x2 t = *(const f32x2*)&P[1][PIDX(w8, n_e, r8, c0)];
        s_lo += t.x;
        s_hi += t.y;
      }
      float u = x_s[8 + r8][s];
      float v_lo = fast_tanh(s_lo + u * win_lo);
      float v_hi = fast_tanh(s_hi + u * win_hi);
      union { f16 h[2]; unsigned int u32; } pk;
      pk.h[0] = (f16)v_lo; pk.h[1] = (f16)v_hi;
      pk.u32  = (pk.u32 & ~1u) | tagw;
      ((unsigned int*)hwr)[houtB] = pk.u32;
      if (!l2mode)
        __hip_atomic_store(&((unsigned int*)mwr)[houtB], pk.u32,
                           __ATOMIC_RELAXED, __HIP_MEMORY_SCOPE_AGENT);
    }
  }
}

// out[b][d] = sum_k h[b][k] * Wout[d][k] + bout[d];  h fp16 from PRIMARY buffer 0
__global__ __launch_bounds__(256) void res_readout_kernel(
    const f16* __restrict__ Hf,       // [256][1024] fp16
    const float* __restrict__ Wout,   // [512][1024]
    const float* __restrict__ bout,   // [512]
    float* __restrict__ out)          // [256][512]
{
  __shared__ f16 hs[16][1032];
  __shared__ f16 wsh[32][1032];
  const int tid = threadIdx.x;
  const int bb = blockIdx.x >> 4;   // batch block (16 rows)
  const int db = blockIdx.x & 15;   // d block (32 cols)

  for (int idx = tid; idx < 2048; idx += 256) {
    int row = idx >> 7, cin = idx & 127;
    *(half8*)&hs[row][cin * 8] = *(const half8*)(Hf + (size_t)(bb * 16 + row) * RES + cin * 8);
  }
  for (int idx = tid; idx < 4096; idx += 256) {
    int row = idx >> 7, cin = idx & 127;
    const float* pw = Wout + (size_t)(db * 32 + row) * RES + cin * 8;
    f32x4 lo = *(const f32x4*)(pw);
    f32x4 hi = *(const f32x4*)(pw + 4);
    half8 f;
#pragma unroll
    for (int j = 0; j < 4; ++j) { f[j] = (f16)lo[j]; f[j + 4] = (f16)hi[j]; }
    *(half8*)&wsh[row][cin * 8] = f;
  }
  __syncthreads();

  const int d  = tid & 31;
  const int bp = tid >> 5;
  float acc0 = 0.f, acc1 = 0.f;
  for (int kc = 0; kc < 128; ++kc) {
    half8 wv = *(const half8*)&wsh[d][kc * 8];
    half8 h0 = *(const half8*)&hs[bp * 2][kc * 8];
    half8 h1 = *(const half8*)&hs[bp * 2 + 1][kc * 8];
#pragma unroll
    for (int j = 0; j < 8; ++j) {
      float wf = (float)wv[j];
      acc0 += wf * (float)h0[j];
      acc1 += wf * (float)h1[j];
    }
  }
  float bo = bout[db * 32 + d];
  out[(size_t)(bb * 16 + bp * 2) * 512 + db * 32 + d]     = acc0 + bo;
  out[(size_t)(bb * 16 + bp * 2 + 1) * 512 + db * 32 + d] = acc1 + bo;
}

extern "C" void kernel_launch(void* const* d_in, const int* in_sizes, int n_in,
                              void* d_out, int out_size, void* d_ws, size_t ws_size,
                              hipStream_t stream) {
  (void)in_sizes; (void)n_in; (void)out_size; (void)ws_size;
  const float* x     = (const float*)d_in[0];
  const float* W_in  = (const float*)d_in[1];
  const float* W_res = (const float*)d_in[2];
  const float* Wout  = (const float*)d_in[3];
  const float* bout  = (const float*)d_in[4];
  float* out = (float*)d_out;

  char* ws = (char*)d_ws;
  f16* hp0 = (f16*)(ws);
  f16* hp1 = (f16*)(ws + (512u << 10));
  f16* hm0 = (f16*)(ws + (1024u << 10));
  f16* hm1 = (f16*)(ws + (1536u << 10));
  unsigned int* xcdmap = (unsigned int*)(ws + (2048u << 10));

  // zero all four H buffers (tags: zeros = valid h0 / invalid first-write) and
  // the xcdmap each launch — erases stale state from previous graph replay.
  hipMemsetAsync(ws, 0, (2048u << 10), stream);
  hipMemsetAsync(ws + (2048u << 10), 0, 1024, stream);

  res_recur_kernel<<<dim3(256), dim3(512), 0, stream>>>(x, W_in, W_res,
                                                        hp0, hp1, hm0, hm1, xcdmap);
  res_readout_kernel<<<dim3(256), dim3(256), 0, stream>>>(hp0, Wout, bout, out);
}